// Round 3
// baseline (165.354 us; speedup 1.0000x reference)
//
#include <hip/hip_runtime.h>
#include <math.h>

// QuadConvLayer: out[b,o,m] = sum_{c,k} kern[o,c,m,k] * f[b,c,k]
// kern has compact support ||x(m,k)|| < 1/6 -> only ~2.2% of the 576
// quadrature points are active per output location m (~13 points).
//
// R3 restructure: ONE BLOCK PER m (grid=144), thread t=(o,c) as before.
//  - No atomics, no output memset: each block owns all (b,o) for its m and
//    writes every OUT[b,o,m] exactly once (zeros when no active points).
//    This deletes the hipMemsetAsync node from the captured graph.
//  - No 48 KB LDS staging: F is 1.18 MB (fully L2-resident). Per active
//    point the b-loop issues 32 independent scalar L2 loads (16 distinct
//    addresses per wave, broadcast to 4 lanes each) -- ILP hides latency.
//  - All 88 MLP weight floats stay in registers (__launch_bounds__(256,2)).
//
// Evidence (R0/R2 rocprof): the two 268 MB fillBufferAligned @ ~40 us each
// are HARNESS poison fills of the output/workspace arenas inside the timed
// region (unchanged when our memset shrank 268MB->288KB). Controllable
// time is only ~15 us: kernel (~14 us est.) + memset dispatch. This round
// attacks exactly that.

#define NQ 24
#define M_TOT 144
#define NB 32

__device__ __forceinline__ float sin_poly(float x) {
    // |x| <= ~0.8 inside bump support; fdlibm coeffs, err < 1e-9
    float z = x * x;
    float r = fmaf(z, 2.7557313707070068e-06f, -1.9841269659586510e-04f);
    r = fmaf(z, r, 8.3333333332248946e-03f);
    r = fmaf(z, r, -1.6666666666666632e-01f);
    return fmaf(x * z, r, x);
}

__global__ __launch_bounds__(256, 2)
void quadconv_kernel(const float* __restrict__ F,    // (32,16,576)
                     const float* __restrict__ OL,   // (144,2)
                     const float* __restrict__ QN,   // (24,)
                     const float* __restrict__ QW,   // (24,)
                     const float* __restrict__ W1,   // (16,16,2,8)
                     const float* __restrict__ W2,   // (16,16,8,8)
                     const float* __restrict__ W3,   // (16,16,8,1)
                     float* __restrict__ OUT) {      // (32,16,144)
    const int m = blockIdx.x;
    const int t = threadIdx.x;
    const int o = t >> 4;
    const int c = t & 15;

    __shared__ float qn_s[NQ], qw_s[NQ];
    if (t < NQ) { qn_s[t] = QN[t]; qw_s[t] = QW[t]; }

    // ---- per-thread MLP weights, kept in registers ----
    float w1r[16], w2r[64], w3r[8];
    {
        const float4* p1 = (const float4*)(W1 + t * 16);
        #pragma unroll
        for (int i = 0; i < 4; ++i) ((float4*)w1r)[i] = p1[i];
        const float4* p2 = (const float4*)(W2 + t * 64);
        #pragma unroll
        for (int i = 0; i < 16; ++i) ((float4*)w2r)[i] = p2[i];
        const float4* p3 = (const float4*)(W3 + t * 8);
        #pragma unroll
        for (int i = 0; i < 2; ++i) ((float4*)w3r)[i] = p3[i];
    }
    __syncthreads();   // qn_s/qw_s ready; the only barrier

    const float ox = OL[2 * m];
    const float oy = OL[2 * m + 1];

    float acc[NB];
    #pragma unroll
    for (int b = 0; b < NB; ++b) acc[b] = 0.0f;

    const float* __restrict__ Fc = F + c * 576;   // hoist channel offset

    for (int ik = 0; ik < NQ; ++ik) {
        const float x1 = oy - qn_s[ik];
        const float x1sq = x1 * x1;
        if (x1sq >= 1.0f / 36.0f) continue;       // block-uniform: row outside support
        const float qwik = qw_s[ik];

        for (int jk = 0; jk < NQ; ++jk) {
            const float x0 = ox - qn_s[jk];
            const float r2 = fmaf(x0, x0, x1sq);
            const float da = 1296.0f * r2 * r2;
            if (da >= 1.0f) continue;             // block-uniform: point outside support

            const float bump = 2.718281828459045f * expf(-1.0f / (1.0f - da));
            const float kscale = bump * qwik * qw_s[jk];

            float h1[8];
            #pragma unroll
            for (int h = 0; h < 8; ++h)
                h1[h] = sin_poly(fmaf(x0, w1r[h], x1 * w1r[8 + h]));

            float wsum = 0.0f;
            #pragma unroll
            for (int g = 0; g < 8; ++g) {
                float z = h1[0] * w2r[g];
                #pragma unroll
                for (int h = 1; h < 8; ++h)
                    z = fmaf(h1[h], w2r[h * 8 + g], z);
                wsum = fmaf(sin_poly(z), w3r[g], wsum);
            }

            const float kv = wsum * kscale;
            const float* __restrict__ fp = Fc + ik * NQ + jk;   // F[b,c,k], b stride 9216
            #pragma unroll
            for (int b = 0; b < NB; ++b)
                acc[b] = fmaf(kv, fp[b * 9216], acc[b]);
        }
    }

    // reduce over c (low 4 lane bits) -> lane c==0 holds sum over input channels
    #pragma unroll
    for (int b = 0; b < NB; ++b) {
        float v = acc[b];
        v += __shfl_xor(v, 1);
        v += __shfl_xor(v, 2);
        v += __shfl_xor(v, 4);
        v += __shfl_xor(v, 8);
        acc[b] = v;
    }
    if (c == 0) {
        // every (b,o,m) written exactly once across the grid -> no memset needed
        #pragma unroll
        for (int b = 0; b < NB; ++b)
            OUT[b * (16 * M_TOT) + o * M_TOT + m] = acc[b];
    }
}

extern "C" void kernel_launch(void* const* d_in, const int* in_sizes, int n_in,
                              void* d_out, int out_size, void* d_ws, size_t ws_size,
                              hipStream_t stream) {
    const float* F  = (const float*)d_in[0];
    const float* OL = (const float*)d_in[1];
    const float* QN = (const float*)d_in[2];
    const float* QW = (const float*)d_in[3];
    const float* W1 = (const float*)d_in[4];
    const float* W2 = (const float*)d_in[5];
    const float* W3 = (const float*)d_in[6];
    float* OUT = (float*)d_out;
    // No memset: the kernel writes the full logical (32,16,144) output
    // directly (one owner block per m), including zeros outside support.
    quadconv_kernel<<<dim3(M_TOT), dim3(256), 0, stream>>>(F, OL, QN, QW, W1, W2, W3, OUT);
}

// Round 4
// 97.626 us; speedup vs baseline: 1.6937x; 1.6937x over previous
//
#include <hip/hip_runtime.h>
#include <math.h>

// QuadConvLayer: out[b,o,m] = sum_{c,k} kern[o,c,m,k] * f[b,c,k]
// kern has compact support ||x(m,k)|| < 1/6 -> ~2.2% of (m,k) active.
//
// R4: back to the verified R0/R2 structure (LDS staging + (row,m) grid +
// atomics; R3's one-block-per-m at 3% occupancy / scattered loads was 105us).
// Two provable cuts vs R0/R2:
//  - Grid (8,144): <=7 ik rows can be active per m (7 smallest consecutive
//    GL-24 gaps sum to 0.4498 > 1/3 support width), so 8 row-rank slots
//    cover all rows; deletes ~2300 dead-block launches of the 24x144 grid.
//  - Stage a float4-aligned 12-wide jk window (24 KB LDS) instead of all
//    24 columns (48 KB): active columns are a contiguous run of <=7 nodes
//    (same gap bound); aligned start wastes <=3 slots, 7+3 <= 12. Halves
//    staging loads, ds_writes, and LDS footprint.
// Harness floor (R0/R2/R3 rocprof): two 268 MB poison fills ~80 us/iter we
// cannot touch; this round attacks the ~14 us controllable kernel slice.

#define NQ 24
#define M_TOT 144
#define NB 32
#define JW 12        // staged jk window width (proof: max 7 active + <=3 align)
#define NROW 8       // row-rank slots (proof: max 7 active rows)

__device__ __forceinline__ float sin_poly(float x) {
    // |x| <= ~0.8 inside bump support; fdlibm coeffs, err < 1e-9
    float z = x * x;
    float r = fmaf(z, 2.7557313707070068e-06f, -1.9841269659586510e-04f);
    r = fmaf(z, r, 8.3333333332248946e-03f);
    r = fmaf(z, r, -1.6666666666666632e-01f);
    return fmaf(x * z, r, x);
}

__global__ __launch_bounds__(256, 2)
void quadconv_kernel(const float* __restrict__ F,    // (32,16,576)
                     const float* __restrict__ OL,   // (144,2)
                     const float* __restrict__ QN,   // (24,)
                     const float* __restrict__ QW,   // (24,)
                     const float* __restrict__ W1,   // (16,16,2,8)
                     const float* __restrict__ W2,   // (16,16,8,8)
                     const float* __restrict__ W3,   // (16,16,8,1)
                     float* __restrict__ OUT) {      // (32,16,144)
    const int r = blockIdx.x;     // active-row rank 0..7
    const int m = blockIdx.y;
    const int t = threadIdx.x;
    const int o = t >> 4;
    const int c = t & 15;

    __shared__ float f_s[JW * 512];    // 24 KB: f_s[jj*512 + b*16 + c]
    __shared__ float qn_s[NQ], qw_s[NQ];

    if (t < NQ) { qn_s[t] = QN[t]; qw_s[t] = QW[t]; }
    __syncthreads();                   // all threads reach this before any exit

    const float ox = OL[2 * m];
    const float oy = OL[2 * m + 1];

    // ---- claim the r-th active ik row (block-uniform scan over LDS) ----
    int ik = -1;
    float x1 = 0.0f;
    {
        int cnt = 0;
        #pragma unroll
        for (int i = 0; i < NQ; ++i) {
            const float d = oy - qn_s[i];
            if (d * d < 1.0f / 36.0f) {
                if (cnt == r) { ik = i; x1 = d; }
                ++cnt;
            }
        }
    }
    if (ik < 0) return;                // fewer than r+1 active rows (uniform)
    const float x1sq = x1 * x1;
    const float qwik = qw_s[ik];

    // ---- find first candidate jk column: (ox-qn)^2 < 1/36 is NECESSARY
    // for da<1 (da = 1296*(x0^2+x1^2)^2 >= 1296*x0^4), and the candidate
    // set is one contiguous run of <=7 nodes. ----
    int lo = NQ;
    #pragma unroll
    for (int i = NQ - 1; i >= 0; --i) {
        const float d = ox - qn_s[i];
        if (d * d < 1.0f / 36.0f) lo = i;
    }
    if (lo == NQ) return;              // row active but no columns (uniform)
    const int jc0 = min(lo & ~3, NQ - JW);   // float4-aligned window start

    // ---- per-thread MLP weights, kept in registers ----
    float w1r[16], w2r[64], w3r[8];
    {
        const float4* p1 = (const float4*)(W1 + t * 16);
        #pragma unroll
        for (int i = 0; i < 4; ++i) ((float4*)w1r)[i] = p1[i];
        const float4* p2 = (const float4*)(W2 + t * 64);
        #pragma unroll
        for (int i = 0; i < 16; ++i) ((float4*)w2r)[i] = p2[i];
        const float4* p3 = (const float4*)(W3 + t * 8);
        #pragma unroll
        for (int i = 0; i < 2; ++i) ((float4*)w3r)[i] = p3[i];
    }

    // ---- stage F[:, :, ik*24+jc0 .. +JW) -> LDS ----
    // pair p = b*16 + c owns JW consecutive k's (48 B, 16B-aligned:
    // b*9216, c*576, ik*24, jc0 all multiples of 4 floats)
    {
        const int kbase = ik * NQ + jc0;
        #pragma unroll
        for (int pp = 0; pp < 2; ++pp) {
            const int p  = t + pp * 256;
            const int b  = p >> 4;
            const int cc = p & 15;
            const float4* src = (const float4*)(F + b * 9216 + cc * 576 + kbase);
            float4 q[JW / 4];
            #pragma unroll
            for (int j = 0; j < JW / 4; ++j) q[j] = src[j];
            const float* qs = (const float*)q;
            #pragma unroll
            for (int j = 0; j < JW; ++j) f_s[j * 512 + p] = qs[j];
        }
    }
    __syncthreads();

    float acc[NB];
    #pragma unroll
    for (int b = 0; b < NB; ++b) acc[b] = 0.0f;
    bool any = false;

    for (int jj = 0; jj < JW; ++jj) {
        const float x0 = ox - qn_s[jc0 + jj];
        const float r2 = fmaf(x0, x0, x1sq);
        const float da = 1296.0f * r2 * r2;
        if (da >= 1.0f) continue;      // block-uniform; identical test to R0/R2

        any = true;
        const float bump = 2.718281828459045f * expf(-1.0f / (1.0f - da));
        const float kscale = bump * qwik * qw_s[jc0 + jj];

        float h1[8];
        #pragma unroll
        for (int h = 0; h < 8; ++h)
            h1[h] = sin_poly(fmaf(x0, w1r[h], x1 * w1r[8 + h]));

        float wsum = 0.0f;
        #pragma unroll
        for (int g = 0; g < 8; ++g) {
            float z = h1[0] * w2r[g];
            #pragma unroll
            for (int h = 1; h < 8; ++h)
                z = fmaf(h1[h], w2r[h * 8 + g], z);
            wsum = fmaf(sin_poly(z), w3r[g], wsum);
        }

        const float kv = wsum * kscale;
        const float* fp = &f_s[jj * 512 + c];
        #pragma unroll
        for (int b = 0; b < NB; ++b)
            acc[b] = fmaf(kv, fp[b * 16], acc[b]);
    }

    if (!any) return;                  // uniform

    // reduce over c (low 4 lane bits), then c==0 lanes accumulate to OUT
    #pragma unroll
    for (int b = 0; b < NB; ++b) {
        float v = acc[b];
        v += __shfl_xor(v, 1);
        v += __shfl_xor(v, 2);
        v += __shfl_xor(v, 4);
        v += __shfl_xor(v, 8);
        acc[b] = v;
    }
    if (c == 0) {
        #pragma unroll
        for (int b = 0; b < NB; ++b)
            atomicAdd(&OUT[b * (16 * M_TOT) + o * M_TOT + m], acc[b]);
    }
}

extern "C" void kernel_launch(void* const* d_in, const int* in_sizes, int n_in,
                              void* d_out, int out_size, void* d_ws, size_t ws_size,
                              hipStream_t stream) {
    const float* F  = (const float*)d_in[0];
    const float* OL = (const float*)d_in[1];
    const float* QN = (const float*)d_in[2];
    const float* QW = (const float*)d_in[3];
    const float* W1 = (const float*)d_in[4];
    const float* W2 = (const float*)d_in[5];
    const float* W3 = (const float*)d_in[6];
    float* OUT = (float*)d_out;
    // Zero only the logical (32,16,144) output region the atomics target.
    const size_t logical_bytes = (size_t)NB * 16 * M_TOT * sizeof(float);
    hipMemsetAsync(d_out, 0, logical_bytes, stream);
    quadconv_kernel<<<dim3(NROW, M_TOT), dim3(256), 0, stream>>>(F, OL, QN, QW, W1, W2, W3, OUT);
}